// Round 4
// baseline (405.675 us; speedup 1.0000x reference)
//
#include <hip/hip_runtime.h>
#include <math.h>

#define D_DIM 3072
#define H_DIM 1024
#define Z_DIM 32
#define BATCH 128
#define NNEI 32
#define NROWS (BATCH * NNEI) /* 4096 */
#define MENC (NROWS + BATCH) /* 4224 */

typedef __attribute__((ext_vector_type(8))) short short8;
typedef __attribute__((ext_vector_type(4))) float f32x4;
typedef unsigned short ushortT;

__device__ __forceinline__ unsigned short f2bf(float f) {
  union { float f; unsigned int u; } v; v.f = f;
  unsigned int r = v.u + 0x7FFFu + ((v.u >> 16) & 1u);
  return (unsigned short)(r >> 16);
}
__device__ __forceinline__ float bf2f(unsigned short b) {
  union { unsigned int u; float f; } v; v.u = ((unsigned int)b) << 16;
  return v.f;
}

// Async global->LDS, 16B per lane. LDS dest is WAVE-UNIFORM base; HW adds
// lane*16. Global src is per-lane.
__device__ __forceinline__ void gl16(const ushortT* g, ushortT* l) {
  typedef __attribute__((address_space(1))) const void gvoid;
  typedef __attribute__((address_space(3))) void lvoid;
  __builtin_amdgcn_global_load_lds((gvoid*)(const void*)g, (lvoid*)(void*)l,
                                   16, 0, 0);
}
#define BAR() asm volatile("s_barrier" ::: "memory")
#define VM0() asm volatile("s_waitcnt vmcnt(0)" ::: "memory")

template <int N>
__device__ __forceinline__ void vmw() {
  if constexpr (N == 0)      asm volatile("s_waitcnt vmcnt(0)" ::: "memory");
  else if constexpr (N == 2) asm volatile("s_waitcnt vmcnt(2)" ::: "memory");
  else if constexpr (N == 3) asm volatile("s_waitcnt vmcnt(3)" ::: "memory");
  else if constexpr (N == 4) asm volatile("s_waitcnt vmcnt(4)" ::: "memory");
  else if constexpr (N == 6) asm volatile("s_waitcnt vmcnt(6)" ::: "memory");
  else if constexpr (N == 8) asm volatile("s_waitcnt vmcnt(8)" ::: "memory");
}

enum { EP_RELU = 0, EP_BIAS = 1, EP_PART = 2, EP_LOSS = 3 };

// R13: ring-4 deep-pipelined GEMM. BM=128, BK=32, LDS ring of 4 tile-slots
// (64KB @TN=128), global_load_lds w16, 3-tile lookahead, per-wave counted
// vmcnt, ONE barrier per tile.
// R12 post-mortem: every pipe <=31% busy, per-block per-iter path 5800 cyc
// -- the 2-barrier structure waits on DMAs issued THE SAME iteration
// (issue-to-wait distance ~0 => full ~1-2k cyc VMEM+DMA latency exposed
// per 32 K-elems; split-K only divided it by #streams). Here tile t's
// loads are issued 3 tiles (~1500+ cyc of compute) before the wait:
//   per tile: vmcnt(NLD*min(ahead,2))  -> my tile-t loads retired (FIFO)
//             s_barrier                -> everyone's tile-t loads landed
//             STAGE(t+3) into slot (t+3)&3  -> safe: old occupant t-1 was
//               fully read before each wave's barrier-t (ds_reads retired
//               pre-MFMA), so post-barrier DMA cannot race readers
//             ds_read + 16 MFMA from slot t&3
// LDS chunk layout per tile-slot (16-row x 32-k chunk = 1KB): addr =
// kq*128 + row*8 ushorts; wave w stages A chunks {2w,2w+1}, B likewise
// (TN=128). Linear in lane order (gload_lds constraint), conflict-free
// b128 reads.
// A: MxK bf16 row-major, BT: NxK bf16. M%128==0, N%TN==0, Ks%32==0.
template <int MODE, int TN>
__global__ __launch_bounds__(256) __attribute__((amdgpu_waves_per_eu(2)))
void gemm32(
    const ushortT* __restrict__ A, const ushortT* __restrict__ BT,
    const float* __restrict__ bias, ushortT* __restrict__ C,
    float* __restrict__ P, int M, int N, int K, int Ks,
    const ushortT* __restrict__ xa,    // EP_LOSS: M x N bf16 (x_nn)
    const float* __restrict__ wrow,    // EP_LOSS: per-row weight
    float* __restrict__ out) {
  constexpr int NF = TN / 32;   // 4 (TN=128), 2 (TN=64), 1 (TN=32)

  __shared__ __align__(16) ushortT As[4][4096];     // 4 x (128 x 32)
  __shared__ __align__(16) ushortT Bs[4][TN * 32];

  const int t = threadIdx.x;
  const int wave = t >> 6;
  const int lane = t & 63;
  const int quad = lane >> 4;
  const int lm = lane & 15;

  // XCD-bijective swizzle (kept: FETCH 105->41MB). Only when nwg%8==0.
  int id = blockIdx.y * gridDim.x + blockIdx.x;
  const int nwg = gridDim.x * gridDim.y;
  if ((nwg & 7) == 0) id = (id & 7) * (nwg >> 3) + (id >> 3);
  const int bm = (id / gridDim.x) * 128;
  const int bn = (id % gridDim.x) * TN;

  const int koff = blockIdx.z * Ks;
  const int wr = (wave >> 1) * 64;
  const int wc = (wave & 1) * (TN / 2);

  f32x4 acc[4][NF];
#pragma unroll
  for (int i = 0; i < 4; ++i)
#pragma unroll
    for (int j = 0; j < NF; ++j) acc[i][j] = (f32x4)0.f;

  // staging: lane l -> (row = l&15, kq = l>>4); wave w owns chunks {2w,2w+1}
  const int srow = lane & 15;
  const int skq = lane >> 4;
  const ushortT* gA =
      A + (size_t)(bm + wave * 32 + srow) * K + koff + skq * 8;
  const size_t row16 = (size_t)16 * K;

  const ushortT* gB;
  if (TN == 128) {
    gB = BT + (size_t)(bn + wave * 32 + srow) * K + koff + skq * 8;
  } else if (TN == 64) {
    gB = BT + (size_t)(bn + wave * 16 + srow) * K + koff + skq * 8;
  } else {  // TN == 32: only waves 0,1 stage B (one chunk each)
    gB = BT + (size_t)(bn + (wave & 1) * 16 + srow) * K + koff + skq * 8;
  }

#define STAGE(kk, sl)                                           \
  {                                                             \
    const size_t o = (size_t)(kk) * 32;                         \
    ushortT* lA = &As[sl][wave * 1024];                         \
    gl16(gA + o, lA);                                           \
    gl16(gA + row16 + o, lA + 512);                             \
    if (TN == 128) {                                            \
      ushortT* lB = &Bs[sl][wave * 1024];                       \
      gl16(gB + o, lB);                                         \
      gl16(gB + row16 + o, lB + 512);                           \
    } else if (TN == 64) {                                      \
      gl16(gB + o, &Bs[sl][wave * 512]);                        \
    } else {                                                    \
      if (wave < 2) gl16(gB + o, &Bs[sl][(wave & 1) * 512]);    \
    }                                                           \
  }

  const int nk = Ks / 32;
  // prologue: 3-deep prefetch (no waits, distinct slots, nobody reads yet)
  for (int p = 0; p < 3 && p < nk; ++p) STAGE(p, p);

  for (int t0 = 0; t0 < nk; ++t0) {
    const int sl = t0 & 3;
    const int ahead = nk - 1 - t0;
    const int a2 = ahead >= 2 ? 2 : ahead;
    // per-wave loads/tile NLD: TN=128 -> 4; TN=64 -> 3; TN=32 -> 3 or 2.
    // outstanding before wait = NLD*(a2+1); retire exactly tile t0's.
    if (TN == 128) {
      if (a2 == 2) vmw<8>(); else if (a2 == 1) vmw<4>(); else vmw<0>();
    } else if (TN == 64) {
      if (a2 == 2) vmw<6>(); else if (a2 == 1) vmw<3>(); else vmw<0>();
    } else {
      if (wave < 2) {
        if (a2 == 2) vmw<6>(); else if (a2 == 1) vmw<3>(); else vmw<0>();
      } else {
        if (a2 == 2) vmw<4>(); else if (a2 == 1) vmw<2>(); else vmw<0>();
      }
    }
    BAR();  // everyone's tile-t0 loads landed; slot (t0+3)&3 free
    if (t0 + 3 < nk) STAGE(t0 + 3, (t0 + 3) & 3);

    const ushortT* arp = &As[sl][(wr >> 4) * 512 + lane * 8];
    const ushortT* brp = &Bs[sl][(wc >> 4) * 512 + lane * 8];
    short8 af[4], bf[NF];
#pragma unroll
    for (int mt = 0; mt < 4; ++mt) af[mt] = *(const short8*)(arp + mt * 512);
#pragma unroll
    for (int nt = 0; nt < NF; ++nt) bf[nt] = *(const short8*)(brp + nt * 512);
#pragma unroll
    for (int mt = 0; mt < 4; ++mt)
#pragma unroll
      for (int nt = 0; nt < NF; ++nt)
        acc[mt][nt] = __builtin_amdgcn_mfma_f32_16x16x32_bf16(
            af[mt], bf[nt], acc[mt][nt], 0, 0, 0);
  }
#undef STAGE

  // C/D layout: col = lane&15, row = quad*4 + reg
  if (MODE == EP_LOSS) {
    __shared__ float red[256];
    float lsum = 0.f;
#pragma unroll
    for (int mt = 0; mt < 4; ++mt) {
#pragma unroll
      for (int r = 0; r < 4; ++r) {
        const int row = bm + wr + mt * 16 + quad * 4 + r;
        const float w = wrow[row];
        const ushortT* xr = xa + (size_t)row * N;
        float rs = 0.f;
#pragma unroll
        for (int nt = 0; nt < NF; ++nt) {
          const int col = bn + wc + nt * 16 + lm;
          const float d = bf2f(xr[col]) - (acc[mt][nt][r] + bias[col]);
          rs = fmaf(d, d, rs);
        }
        lsum = fmaf(w, rs, lsum);
      }
    }
    __syncthreads();
    red[t] = lsum;
    __syncthreads();
    for (int st = 128; st > 0; st >>= 1) {
      if (t < st) red[t] += red[t + st];
      __syncthreads();
    }
    if (t == 0) atomicAdd(out, red[0] * (1.0f / (float)NROWS));
  } else if (MODE == EP_PART) {
#pragma unroll
    for (int mt = 0; mt < 4; ++mt)
#pragma unroll
      for (int r = 0; r < 4; ++r) {
        const int row = bm + wr + mt * 16 + quad * 4 + r;
#pragma unroll
        for (int nt = 0; nt < NF; ++nt) {
          const int col = bn + wc + nt * 16 + lm;
          P[((size_t)blockIdx.z * M + row) * N + col] = acc[mt][nt][r];
        }
      }
  } else {
#pragma unroll
    for (int mt = 0; mt < 4; ++mt)
#pragma unroll
      for (int r = 0; r < 4; ++r) {
        const int row = bm + wr + mt * 16 + quad * 4 + r;
#pragma unroll
        for (int nt = 0; nt < NF; ++nt) {
          const int col = bn + wc + nt * 16 + lm;
          float v = acc[mt][nt][r] + bias[col];
          if (MODE == EP_RELU) v = fmaxf(v, 0.f);
          C[(size_t)row * N + col] = f2bf(v);
        }
      }
  }
}

// Single K=32 tile GEMM (dec L1 only): gload_lds + vmcnt(0) + one compute.
template <int MODE, int TN>
__global__ __launch_bounds__(256) void gemm_sb(
    const ushortT* __restrict__ A, const ushortT* __restrict__ BT,
    const float* __restrict__ bias, ushortT* __restrict__ C,
    int M, int N, int K,   // K must be 32
    const ushortT* __restrict__ xa, const float* __restrict__ wrow,
    float* __restrict__ out) {
  constexpr int NF = TN / 32;
  __shared__ __align__(16) ushortT As[4096];
  __shared__ __align__(16) ushortT Bs[TN * 32];

  const int t = threadIdx.x;
  const int wave = t >> 6;
  const int lane = t & 63;
  const int quad = lane >> 4;
  const int lm = lane & 15;

  int id = blockIdx.y * gridDim.x + blockIdx.x;
  const int nwg = gridDim.x * gridDim.y;
  if ((nwg & 7) == 0) id = (id & 7) * (nwg >> 3) + (id >> 3);
  const int bm = (id / gridDim.x) * 128;
  const int bn = (id % gridDim.x) * TN;

  const int wr = (wave >> 1) * 64;
  const int wc = (wave & 1) * (TN / 2);

  const int a_r0 = (t >> 6) * 16 + (t & 15);
  const int a_q8 = ((t >> 4) & 3) * 8;
  const ushortT* ga0 = A + (size_t)(bm + a_r0) * K + a_q8;
  const ushortT* gb0 = BT + (size_t)(bn + a_r0) * K + a_q8;

  ushortT* asw = &As[wave * 512];
  ushortT* bsw = &Bs[wave * 512];
  gl16(ga0, asw);
  gl16(ga0 + (size_t)64 * K, asw + 2048);
  gl16(gb0, bsw);
  if (TN == 128) gl16(gb0 + (size_t)64 * K, bsw + 2048);
  VM0();
  BAR();

  f32x4 acc[4][NF];
#pragma unroll
  for (int i = 0; i < 4; ++i)
#pragma unroll
    for (int j = 0; j < NF; ++j) acc[i][j] = (f32x4)0.f;

  const ushortT* arp = As + (wr >> 4) * 512 + lane * 8;
  const ushortT* brp = Bs + (wc >> 4) * 512 + lane * 8;
  short8 af[4], bf[NF];
#pragma unroll
  for (int mt = 0; mt < 4; ++mt) af[mt] = *(const short8*)(arp + mt * 512);
#pragma unroll
  for (int nt = 0; nt < NF; ++nt) bf[nt] = *(const short8*)(brp + nt * 512);
#pragma unroll
  for (int mt = 0; mt < 4; ++mt)
#pragma unroll
    for (int nt = 0; nt < NF; ++nt)
      acc[mt][nt] = __builtin_amdgcn_mfma_f32_16x16x32_bf16(
          af[mt], bf[nt], acc[mt][nt], 0, 0, 0);

#pragma unroll
  for (int mt = 0; mt < 4; ++mt)
#pragma unroll
    for (int r = 0; r < 4; ++r) {
      const int row = bm + wr + mt * 16 + quad * 4 + r;
#pragma unroll
      for (int nt = 0; nt < NF; ++nt) {
        const int col = bn + wc + nt * 16 + lm;
        float v = acc[mt][nt][r] + bias[col];
        if (MODE == EP_RELU) v = fmaxf(v, 0.f);
        C[(size_t)row * N + col] = f2bf(v);
      }
    }
}

// sum split-K fp32 partials + bias (+optional relu) -> bf16. N power of 2.
template <int S, int RELU>
__global__ __launch_bounds__(256) void reduce_lin(
    const float* __restrict__ P, const float* __restrict__ bias,
    ushortT* __restrict__ outp, int MN, int Nmask) {
  const int i4 = (blockIdx.x * 256 + threadIdx.x) * 4;
  if (i4 >= MN) return;
  float4 s = *(const float4*)(P + i4);
#pragma unroll
  for (int k = 1; k < S; ++k) {
    const float4 q = *(const float4*)(P + (size_t)k * MN + i4);
    s.x += q.x; s.y += q.y; s.z += q.z; s.w += q.w;
  }
  const float4 b = *(const float4*)(bias + (i4 & Nmask));
  float vx = s.x + b.x, vy = s.y + b.y, vz = s.z + b.z, vw = s.w + b.w;
  if (RELU) {
    vx = fmaxf(vx, 0.f); vy = fmaxf(vy, 0.f);
    vz = fmaxf(vz, 0.f); vw = fmaxf(vw, 0.f);
  }
  ushort4 o;
  o.x = f2bf(vx); o.y = f2bf(vy); o.z = f2bf(vz); o.w = f2bf(vw);
  *(ushort4*)(outp + i4) = o;
}

// Frozen-mask apply on raw pre-activations U (rows x 1024 bf16):
// rows < 4096 (neighbors): out = (U[center_row] > 0) ? U : 0
// rows >= 4096 (centers):  out = relu(U)
__global__ __launch_bounds__(256) void mask_apply(
    const ushortT* __restrict__ U, ushortT* __restrict__ outp) {
  const int i4 = (blockIdx.x * 256 + threadIdx.x) * 4;
  const int r = i4 >> 10;
  const int c = i4 & 1023;
  ushort4 u = *(const ushort4*)(U + i4);
  ushort4 o;
  if (r < NROWS) {
    const ushort4 m = *(const ushort4*)(U + (((size_t)(NROWS + (r >> 5))) << 10) + c);
    o.x = ((short)m.x > 0) ? u.x : 0;
    o.y = ((short)m.y > 0) ? u.y : 0;
    o.z = ((short)m.z > 0) ? u.z : 0;
    o.w = ((short)m.w > 0) ? u.w : 0;
  } else {
    o.x = ((short)u.x > 0) ? u.x : 0;
    o.y = ((short)u.y > 0) ? u.y : 0;
    o.z = ((short)u.z > 0) ? u.z : 0;
    o.w = ((short)u.w > 0) ? u.w : 0;
  }
  *(ushort4*)(outp + i4) = o;
}

// Fused prep: x fp32 -> bf16 A_enc; per-(b,n) weights from dist^2; zero out[0].
__global__ __launch_bounds__(256) void prep_kernel(
    const float* __restrict__ x_c, const float* __restrict__ x_nn,
    ushortT* __restrict__ A_enc, float* __restrict__ wbuf, float* __restrict__ out) {
  const int i = blockIdx.x;
  const int t = threadIdx.x;
  if (i < NROWS) {
    const float* src = x_nn + (size_t)i * D_DIM;
    const float* ctr = x_c + (size_t)(i >> 5) * D_DIM;
    ushortT* dst = A_enc + (size_t)i * D_DIM;
    float s = 0.f;
    for (int d = t * 4; d < D_DIM; d += 1024) {
      const float4 v = *(const float4*)(src + d);
      const float4 c = *(const float4*)(ctr + d);
      ushort4 o;
      o.x = f2bf(v.x); o.y = f2bf(v.y); o.z = f2bf(v.z); o.w = f2bf(v.w);
      *(ushort4*)(dst + d) = o;
      const float dx = v.x - c.x, dy = v.y - c.y, dz = v.z - c.z, dw = v.w - c.w;
      s += dx * dx + dy * dy + dz * dz + dw * dw;
    }
    __shared__ float red[256];
    red[t] = s;
    __syncthreads();
    for (int st = 128; st > 0; st >>= 1) {
      if (t < st) red[t] += red[t + st];
      __syncthreads();
    }
    if (t == 0) {
      wbuf[i] = (red[0] > 1e-24f) ? 1.0f : 0.5f;
      if (i == 0) out[0] = 0.f;
    }
  } else {
    const int r = i - NROWS;
    const float* src = x_c + (size_t)r * D_DIM;
    ushortT* dst = A_enc + (size_t)i * D_DIM;
    for (int d = t * 4; d < D_DIM; d += 1024) {
      const float4 v = *(const float4*)(src + d);
      ushort4 o;
      o.x = f2bf(v.x); o.y = f2bf(v.y); o.z = f2bf(v.z); o.w = f2bf(v.w);
      *(ushort4*)(dst + d) = o;
    }
  }
}

// Batched transpose+cast of all six weights: W (KxN f32) -> WT (NxK bf16).
__global__ __launch_bounds__(256) void trans_all(
    const float* __restrict__ We1, const float* __restrict__ We2,
    const float* __restrict__ We3, const float* __restrict__ Wd1,
    const float* __restrict__ Wd2, const float* __restrict__ Wd3,
    ushortT* __restrict__ We1T, ushortT* __restrict__ We2T,
    ushortT* __restrict__ We3T, ushortT* __restrict__ Wd1T,
    ushortT* __restrict__ Wd2T, ushortT* __restrict__ Wd3T) {
  const int b = blockIdx.x;
  const float* W; ushortT* WT; int K, N, loc;
  if (b < 3072)      { W = We1; WT = We1T; K = 3072; N = 1024; loc = b; }
  else if (b < 4096) { W = We2; WT = We2T; K = 1024; N = 1024; loc = b - 3072; }
  else if (b < 4128) { W = We3; WT = We3T; K = 1024; N = 32;   loc = b - 4096; }
  else if (b < 4160) { W = Wd1; WT = Wd1T; K = 32;   N = 1024; loc = b - 4128; }
  else if (b < 5184) { W = Wd2; WT = Wd2T; K = 1024; N = 1024; loc = b - 4160; }
  else               { W = Wd3; WT = Wd3T; K = 1024; N = 3072; loc = b - 5184; }
  const int ntiles = N >> 5;
  const int n0 = (loc % ntiles) * 32;
  const int k0 = (loc / ntiles) * 32;
  __shared__ float tile[32][33];
  const int tx = threadIdx.x & 31;
  const int ty = threadIdx.x >> 5;
  for (int i = ty; i < 32; i += 8)
    tile[i][tx] = W[(size_t)(k0 + i) * N + n0 + tx];
  __syncthreads();
  for (int i = ty; i < 32; i += 8)
    WT[(size_t)(n0 + i) * K + k0 + tx] = f2bf(tile[tx][i]);
}

extern "C" void kernel_launch(void* const* d_in, const int* in_sizes, int n_in,
                              void* d_out, int out_size, void* d_ws, size_t ws_size,
                              hipStream_t stream) {
  const float* x_c = (const float*)d_in[0];
  const float* x_nn = (const float*)d_in[1];
  const float* We1 = (const float*)d_in[2];
  const float* be1 = (const float*)d_in[3];
  const float* We2 = (const float*)d_in[4];
  const float* be2 = (const float*)d_in[5];
  const float* We3 = (const float*)d_in[6];
  const float* be3 = (const float*)d_in[7];
  const float* Wd1 = (const float*)d_in[8];
  const float* bd1 = (const float*)d_in[9];
  const float* Wd2 = (const float*)d_in[10];
  const float* bd2 = (const float*)d_in[11];
  const float* Wd3 = (const float*)d_in[12];
  const float* bd3 = (const float*)d_in[13];
  float* out = (float*)d_out;

  char* p = (char*)d_ws;
  auto alloc = [&](size_t bytes) {
    char* r = p;
    p += (bytes + 255) & ~(size_t)255;
    return r;
  };
  ushortT* We1T = (ushortT*)alloc((size_t)H_DIM * D_DIM * 2);
  ushortT* We2T = (ushortT*)alloc((size_t)H_DIM * H_DIM * 2);
  ushortT* We3T = (ushortT*)alloc((size_t)Z_DIM * H_DIM * 2);
  ushortT* Wd1T = (ushortT*)alloc((size_t)H_DIM * Z_DIM * 2);
  ushortT* Wd2T = (ushortT*)alloc((size_t)H_DIM * H_DIM * 2);
  ushortT* Wd3T = (ushortT*)alloc((size_t)D_DIM * H_DIM * 2);
  ushortT* A_enc = (ushortT*)alloc((size_t)MENC * D_DIM * 2);
  ushortT* bufX = (ushortT*)alloc((size_t)MENC * H_DIM * 2);  // h1 / U1 / U2
  ushortT* bufY = (ushortT*)alloc((size_t)MENC * H_DIM * 2);  // h2 / A2 / t2
  ushortT* z = (ushortT*)alloc((size_t)MENC * Z_DIM * 2);
  // shared split-K partial buffer: max(3 planes of MENCxH f32, 8 of MENCxZ)
  float* Pbig = (float*)alloc((size_t)3 * MENC * H_DIM * 4);
  float* wbuf = (float*)alloc((size_t)NROWS * 4);

  const dim3 blk(256);
  const float* nofp = nullptr;
  const ushortT* nobf = nullptr;

  // x -> bf16, per-neighbor weights, zero loss accumulator; weights -> bf16^T
  prep_kernel<<<dim3(MENC), blk, 0, stream>>>(x_c, x_nn, A_enc, wbuf, out);
  trans_all<<<dim3(8256), blk, 0, stream>>>(We1, We2, We3, Wd1, Wd2, Wd3,
                                            We1T, We2T, We3T, Wd1T, Wd2T, Wd3T);

  // enc1: h1 = relu(A_enc @ We1 + be1). Split-K S=3 -> 792 blocks.
  gemm32<EP_PART, 128><<<dim3(8, 33, 3), blk, 0, stream>>>(
      A_enc, We1T, nofp, nullptr, Pbig, MENC, H_DIM, D_DIM, D_DIM / 3,
      nobf, nofp, nullptr);
  reduce_lin<3, 1><<<dim3((MENC * H_DIM) / 1024), blk, 0, stream>>>(
      Pbig, be1, bufX, MENC * H_DIM, H_DIM - 1);

  // enc2: h2 = relu(h1 @ We2 + be2). Split-K S=2 -> 528 blocks.
  gemm32<EP_PART, 128><<<dim3(8, 33, 2), blk, 0, stream>>>(
      bufX, We2T, nofp, nullptr, Pbig, MENC, H_DIM, H_DIM, H_DIM / 2,
      nobf, nofp, nullptr);
  reduce_lin<2, 1><<<dim3((MENC * H_DIM) / 1024), blk, 0, stream>>>(
      Pbig, be2, bufY, MENC * H_DIM, H_DIM - 1);

  // z = h2 @ We3 + be3 (N=32): split-K S=8 -> 264 blocks, 4 tiles each
  gemm32<EP_PART, 32><<<dim3(1, 33, 8), blk, 0, stream>>>(
      bufY, We3T, nofp, nullptr, Pbig, MENC, Z_DIM, H_DIM, H_DIM / 8,
      nobf, nofp, nullptr);
  reduce_lin<8, 0><<<dim3((MENC * Z_DIM) / 1024), blk, 0, stream>>>(
      Pbig, be3, z, MENC * Z_DIM, Z_DIM - 1);

  // linearized decoder with frozen center masks (exact for ReLU MLP):
  // U1 = [z_nn; z_c] @ Wd1 + bd1 (K=32, single tile)
  gemm_sb<EP_BIAS, 64><<<dim3(16, 33), blk, 0, stream>>>(
      z, Wd1T, bd1, bufX, MENC, H_DIM, Z_DIM, nobf, nofp, nullptr);
  // A2 = mask1 .* U1 (neighbors), relu(U1) (centers)
  mask_apply<<<dim3((MENC * H_DIM) / 1024), blk, 0, stream>>>(bufX, bufY);
  // U2 = A2 @ Wd2 + bd2 (raw, all rows). Split-K S=2.
  gemm32<EP_PART, 128><<<dim3(8, 33, 2), blk, 0, stream>>>(
      bufY, Wd2T, nofp, nullptr, Pbig, MENC, H_DIM, H_DIM, H_DIM / 2,
      nobf, nofp, nullptr);
  reduce_lin<2, 0><<<dim3((MENC * H_DIM) / 1024), blk, 0, stream>>>(
      Pbig, bd2, bufX, MENC * H_DIM, H_DIM - 1);
  // t2 = mask2 .* U2 (neighbor rows only)
  mask_apply<<<dim3((NROWS * H_DIM) / 1024), blk, 0, stream>>>(bufX, bufY);
  // loss GEMM: pred = t2 @ Wd3 + bd3, fused weighted-SSE vs bf16 x_nn
  gemm32<EP_LOSS, 128><<<dim3(24, 32, 1), blk, 0, stream>>>(
      bufY, Wd3T, bd3, nullptr, nullptr, NROWS, D_DIM, H_DIM, H_DIM,
      A_enc, wbuf, out);
}

// Round 5
// 368.885 us; speedup vs baseline: 1.0997x; 1.0997x over previous
//
#include <hip/hip_runtime.h>
#include <math.h>

#define D_DIM 3072
#define H_DIM 1024
#define Z_DIM 32
#define BATCH 128
#define NNEI 32
#define NROWS (BATCH * NNEI) /* 4096 */
#define MENC (NROWS + BATCH) /* 4224 */

typedef __attribute__((ext_vector_type(8))) short short8;
typedef __attribute__((ext_vector_type(4))) float f32x4;
typedef unsigned short ushortT;

__device__ __forceinline__ unsigned short f2bf(float f) {
  union { float f; unsigned int u; } v; v.f = f;
  unsigned int r = v.u + 0x7FFFu + ((v.u >> 16) & 1u);
  return (unsigned short)(r >> 16);
}
__device__ __forceinline__ float bf2f(unsigned short b) {
  union { unsigned int u; float f; } v; v.u = ((unsigned int)b) << 16;
  return v.f;
}

// Async global->LDS, 16B per lane. LDS dest is WAVE-UNIFORM base; HW adds
// lane*16. Global src is per-lane.
__device__ __forceinline__ void gl16(const ushortT* g, ushortT* l) {
  typedef __attribute__((address_space(1))) const void gvoid;
  typedef __attribute__((address_space(3))) void lvoid;
  __builtin_amdgcn_global_load_lds((gvoid*)(const void*)g, (lvoid*)(void*)l,
                                   16, 0, 0);
}

// Inline-asm ds_read_b128: INVISIBLE to the compiler's waitcnt pass.
// R14 rationale: SIInsertWaitcnts inserts a conservative vmcnt(0) before
// C++ ds_reads that may alias outstanding global_load_lds DMAs (runtime-
// indexed slots of one __shared__ array are non-disambiguable). That drain
// defeated every pipeline (R11/R12/R13: per-tile serial pinned ~3000 cyc).
// Completion is OUR job: s_waitcnt lgkmcnt(0) + sched_barrier(0) before
// the MFMAs (rule 18: without the sched_barrier, hipcc hoists register-only
// MFMAs past the asm lgkmcnt).
typedef __attribute__((address_space(3))) const ushortT lds_cus;
__device__ __forceinline__ short8 ldsr(const ushortT* p) {
  short8 r;
  asm volatile("ds_read_b128 %0, %1" : "=v"(r) : "v"((lds_cus*)p));
  return r;
}

#define BAR() asm volatile("s_barrier" ::: "memory")
#define VM0() asm volatile("s_waitcnt vmcnt(0)" ::: "memory")
#define LGKM0() asm volatile("s_waitcnt lgkmcnt(0)" ::: "memory")

template <int N>
__device__ __forceinline__ void vmw() {
  if constexpr (N == 0)      asm volatile("s_waitcnt vmcnt(0)" ::: "memory");
  else if constexpr (N == 2) asm volatile("s_waitcnt vmcnt(2)" ::: "memory");
  else if constexpr (N == 3) asm volatile("s_waitcnt vmcnt(3)" ::: "memory");
  else if constexpr (N == 4) asm volatile("s_waitcnt vmcnt(4)" ::: "memory");
}

enum { EP_RELU = 0, EP_BIAS = 1, EP_PART = 2, EP_LOSS = 3 };

// R14: ring-3 pipelined GEMM, asm ds_read. BM=128, BK=32, LDS ring of 3
// tile-slots (48KB @TN=128 -> 3 blocks/CU incl. loss GEMM), gl16 staging,
// 2-tile lookahead, ONE barrier per tile, counted vmcnt.
// Per tile t:  vmw<NLD>  -> my tile-t DMAs retired (only tile-(t+1)'s NLD
//                           loads remain; t's were issued 2 iters ago)
//              s_barrier -> everyone's tile-t loads landed; slot (t+2)%3
//                           free (its occupant t-1 was read last iter, and
//                           those asm ds_reads completed at last iter's
//                           lgkmcnt(0))
//              STAGE(t+2) into slot (t+2)%3
//              8 x asm ds_read_b128 ; lgkmcnt(0) ; sched_barrier(0)
//              16 x MFMA
// LDS chunk layout per slot (16-row x 32-k chunk = 1KB): addr = kq*128 +
// row*8 ushorts; wave w stages A chunks {2w,2w+1} (B likewise at TN=128).
// Linear in lane order (gload_lds constraint), conflict-free b128 reads.
// A: MxK bf16 row-major, BT: NxK bf16. M%128==0, N%TN==0, Ks%32==0, nk>=2.
template <int MODE, int TN>
__global__ __launch_bounds__(256) __attribute__((amdgpu_waves_per_eu(3)))
void gemm32(
    const ushortT* __restrict__ A, const ushortT* __restrict__ BT,
    const float* __restrict__ bias, ushortT* __restrict__ C,
    float* __restrict__ P, int M, int N, int K, int Ks,
    const ushortT* __restrict__ xa,    // EP_LOSS: M x N bf16 (x_nn)
    const float* __restrict__ wrow,    // EP_LOSS: per-row weight
    float* __restrict__ out) {
  constexpr int NF = TN / 32;   // 4 (TN=128), 2 (TN=64), 1 (TN=32)

  __shared__ __align__(16) ushortT As[3][4096];     // 3 x (128 x 32)
  __shared__ __align__(16) ushortT Bs[3][TN * 32];

  const int t = threadIdx.x;
  const int wave = t >> 6;
  const int lane = t & 63;
  const int quad = lane >> 4;
  const int lm = lane & 15;

  // XCD-bijective swizzle (kept: FETCH 105->41MB). Only when nwg%8==0.
  int id = blockIdx.y * gridDim.x + blockIdx.x;
  const int nwg = gridDim.x * gridDim.y;
  if ((nwg & 7) == 0) id = (id & 7) * (nwg >> 3) + (id >> 3);
  const int bm = (id / gridDim.x) * 128;
  const int bn = (id % gridDim.x) * TN;

  const int koff = blockIdx.z * Ks;
  const int wr = (wave >> 1) * 64;
  const int wc = (wave & 1) * (TN / 2);

  f32x4 acc[4][NF];
#pragma unroll
  for (int i = 0; i < 4; ++i)
#pragma unroll
    for (int j = 0; j < NF; ++j) acc[i][j] = (f32x4)0.f;

  // staging: lane l -> (row = l&15, kq = l>>4); wave w owns chunks {2w,2w+1}
  const int srow = lane & 15;
  const int skq = lane >> 4;
  const ushortT* gA =
      A + (size_t)(bm + wave * 32 + srow) * K + koff + skq * 8;
  const size_t row16 = (size_t)16 * K;

  const ushortT* gB;
  if (TN == 128) {
    gB = BT + (size_t)(bn + wave * 32 + srow) * K + koff + skq * 8;
  } else if (TN == 64) {
    gB = BT + (size_t)(bn + wave * 16 + srow) * K + koff + skq * 8;
  } else {  // TN == 32: only waves 0,1 stage B (one chunk each)
    gB = BT + (size_t)(bn + (wave & 1) * 16 + srow) * K + koff + skq * 8;
  }

#define STAGE(kk, sl)                                           \
  {                                                             \
    const size_t o = (size_t)(kk) * 32;                         \
    ushortT* lA = &As[sl][wave * 1024];                         \
    gl16(gA + o, lA);                                           \
    gl16(gA + row16 + o, lA + 512);                             \
    if (TN == 128) {                                            \
      ushortT* lB = &Bs[sl][wave * 1024];                       \
      gl16(gB + o, lB);                                         \
      gl16(gB + row16 + o, lB + 512);                           \
    } else if (TN == 64) {                                      \
      gl16(gB + o, &Bs[sl][wave * 512]);                        \
    } else {                                                    \
      if (wave < 2) gl16(gB + o, &Bs[sl][(wave & 1) * 512]);    \
    }                                                           \
  }

  const int nk = Ks / 32;
  // prologue: 2-deep prefetch into slots 0,1
  STAGE(0, 0);
  if (nk > 1) STAGE(1, 1);

  int sl = 0;          // slot holding current tile
  int sn = 2;          // slot to stage (t0+2) into
  for (int t0 = 0; t0 < nk; ++t0) {
    // retire tile t0's DMAs: only tile-(t0+1)'s NLD loads may remain
    if (t0 + 1 < nk) {
      if (TN == 128) vmw<4>();
      else if (TN == 64) vmw<3>();
      else { if (wave < 2) vmw<3>(); else vmw<2>(); }
    } else {
      vmw<0>();
    }
    BAR();  // everyone's tile-t0 loads landed; slot sn free
    if (t0 + 2 < nk) STAGE(t0 + 2, sn);

    const ushortT* arp = &As[sl][(wr >> 4) * 512 + lane * 8];
    const ushortT* brp = &Bs[sl][(wc >> 4) * 512 + lane * 8];
    short8 af[4], bf[NF];
#pragma unroll
    for (int mt = 0; mt < 4; ++mt) af[mt] = ldsr(arp + mt * 512);
#pragma unroll
    for (int nt = 0; nt < NF; ++nt) bf[nt] = ldsr(brp + nt * 512);
    LGKM0();
    __builtin_amdgcn_sched_barrier(0);
#pragma unroll
    for (int mt = 0; mt < 4; ++mt)
#pragma unroll
      for (int nt = 0; nt < NF; ++nt)
        acc[mt][nt] = __builtin_amdgcn_mfma_f32_16x16x32_bf16(
            af[mt], bf[nt], acc[mt][nt], 0, 0, 0);

    sl = (sl == 2) ? 0 : sl + 1;
    sn = (sn == 2) ? 0 : sn + 1;
  }
#undef STAGE

  // C/D layout: col = lane&15, row = quad*4 + reg
  if (MODE == EP_LOSS) {
    __shared__ float red[256];
    float lsum = 0.f;
#pragma unroll
    for (int mt = 0; mt < 4; ++mt) {
#pragma unroll
      for (int r = 0; r < 4; ++r) {
        const int row = bm + wr + mt * 16 + quad * 4 + r;
        const float w = wrow[row];
        const ushortT* xr = xa + (size_t)row * N;
        float rs = 0.f;
#pragma unroll
        for (int nt = 0; nt < NF; ++nt) {
          const int col = bn + wc + nt * 16 + lm;
          const float d = bf2f(xr[col]) - (acc[mt][nt][r] + bias[col]);
          rs = fmaf(d, d, rs);
        }
        lsum = fmaf(w, rs, lsum);
      }
    }
    __syncthreads();
    red[t] = lsum;
    __syncthreads();
    for (int st = 128; st > 0; st >>= 1) {
      if (t < st) red[t] += red[t + st];
      __syncthreads();
    }
    if (t == 0) atomicAdd(out, red[0] * (1.0f / (float)NROWS));
  } else if (MODE == EP_PART) {
#pragma unroll
    for (int mt = 0; mt < 4; ++mt)
#pragma unroll
      for (int r = 0; r < 4; ++r) {
        const int row = bm + wr + mt * 16 + quad * 4 + r;
#pragma unroll
        for (int nt = 0; nt < NF; ++nt) {
          const int col = bn + wc + nt * 16 + lm;
          P[((size_t)blockIdx.z * M + row) * N + col] = acc[mt][nt][r];
        }
      }
  } else {
#pragma unroll
    for (int mt = 0; mt < 4; ++mt)
#pragma unroll
      for (int r = 0; r < 4; ++r) {
        const int row = bm + wr + mt * 16 + quad * 4 + r;
#pragma unroll
        for (int nt = 0; nt < NF; ++nt) {
          const int col = bn + wc + nt * 16 + lm;
          float v = acc[mt][nt][r] + bias[col];
          if (MODE == EP_RELU) v = fmaxf(v, 0.f);
          C[(size_t)row * N + col] = f2bf(v);
        }
      }
  }
}

// Single K=32 tile GEMM (dec L1 only): gload_lds + vmcnt(0) + one compute.
template <int MODE, int TN>
__global__ __launch_bounds__(256) void gemm_sb(
    const ushortT* __restrict__ A, const ushortT* __restrict__ BT,
    const float* __restrict__ bias, ushortT* __restrict__ C,
    int M, int N, int K,   // K must be 32
    const ushortT* __restrict__ xa, const float* __restrict__ wrow,
    float* __restrict__ out) {
  constexpr int NF = TN / 32;
  __shared__ __align__(16) ushortT As[4096];
  __shared__ __align__(16) ushortT Bs[TN * 32];

  const int t = threadIdx.x;
  const int wave = t >> 6;
  const int lane = t & 63;
  const int quad = lane >> 4;
  const int lm = lane & 15;

  int id = blockIdx.y * gridDim.x + blockIdx.x;
  const int nwg = gridDim.x * gridDim.y;
  if ((nwg & 7) == 0) id = (id & 7) * (nwg >> 3) + (id >> 3);
  const int bm = (id / gridDim.x) * 128;
  const int bn = (id % gridDim.x) * TN;

  const int wr = (wave >> 1) * 64;
  const int wc = (wave & 1) * (TN / 2);

  const int a_r0 = (t >> 6) * 16 + (t & 15);
  const int a_q8 = ((t >> 4) & 3) * 8;
  const ushortT* ga0 = A + (size_t)(bm + a_r0) * K + a_q8;
  const ushortT* gb0 = BT + (size_t)(bn + a_r0) * K + a_q8;

  ushortT* asw = &As[wave * 512];
  ushortT* bsw = &Bs[wave * 512];
  gl16(ga0, asw);
  gl16(ga0 + (size_t)64 * K, asw + 2048);
  gl16(gb0, bsw);
  if (TN == 128) gl16(gb0 + (size_t)64 * K, bsw + 2048);
  VM0();
  BAR();

  f32x4 acc[4][NF];
#pragma unroll
  for (int i = 0; i < 4; ++i)
#pragma unroll
    for (int j = 0; j < NF; ++j) acc[i][j] = (f32x4)0.f;

  const ushortT* arp = As + (wr >> 4) * 512 + lane * 8;
  const ushortT* brp = Bs + (wc >> 4) * 512 + lane * 8;
  short8 af[4], bf[NF];
#pragma unroll
  for (int mt = 0; mt < 4; ++mt) af[mt] = ldsr(arp + mt * 512);
#pragma unroll
  for (int nt = 0; nt < NF; ++nt) bf[nt] = ldsr(brp + nt * 512);
  LGKM0();
  __builtin_amdgcn_sched_barrier(0);
#pragma unroll
  for (int mt = 0; mt < 4; ++mt)
#pragma unroll
    for (int nt = 0; nt < NF; ++nt)
      acc[mt][nt] = __builtin_amdgcn_mfma_f32_16x16x32_bf16(
          af[mt], bf[nt], acc[mt][nt], 0, 0, 0);

#pragma unroll
  for (int mt = 0; mt < 4; ++mt)
#pragma unroll
    for (int r = 0; r < 4; ++r) {
      const int row = bm + wr + mt * 16 + quad * 4 + r;
#pragma unroll
      for (int nt = 0; nt < NF; ++nt) {
        const int col = bn + wc + nt * 16 + lm;
        float v = acc[mt][nt][r] + bias[col];
        if (MODE == EP_RELU) v = fmaxf(v, 0.f);
        C[(size_t)row * N + col] = f2bf(v);
      }
    }
}

// sum split-K fp32 partials + bias (+optional relu) -> bf16. N power of 2.
template <int S, int RELU>
__global__ __launch_bounds__(256) void reduce_lin(
    const float* __restrict__ P, const float* __restrict__ bias,
    ushortT* __restrict__ outp, int MN, int Nmask) {
  const int i4 = (blockIdx.x * 256 + threadIdx.x) * 4;
  if (i4 >= MN) return;
  float4 s = *(const float4*)(P + i4);
#pragma unroll
  for (int k = 1; k < S; ++k) {
    const float4 q = *(const float4*)(P + (size_t)k * MN + i4);
    s.x += q.x; s.y += q.y; s.z += q.z; s.w += q.w;
  }
  const float4 b = *(const float4*)(bias + (i4 & Nmask));
  float vx = s.x + b.x, vy = s.y + b.y, vz = s.z + b.z, vw = s.w + b.w;
  if (RELU) {
    vx = fmaxf(vx, 0.f); vy = fmaxf(vy, 0.f);
    vz = fmaxf(vz, 0.f); vw = fmaxf(vw, 0.f);
  }
  ushort4 o;
  o.x = f2bf(vx); o.y = f2bf(vy); o.z = f2bf(vz); o.w = f2bf(vw);
  *(ushort4*)(outp + i4) = o;
}

// Frozen-mask apply on raw pre-activations U (rows x 1024 bf16):
// rows < 4096 (neighbors): out = (U[center_row] > 0) ? U : 0
// rows >= 4096 (centers):  out = relu(U)
__global__ __launch_bounds__(256) void mask_apply(
    const ushortT* __restrict__ U, ushortT* __restrict__ outp) {
  const int i4 = (blockIdx.x * 256 + threadIdx.x) * 4;
  const int r = i4 >> 10;
  const int c = i4 & 1023;
  ushort4 u = *(const ushort4*)(U + i4);
  ushort4 o;
  if (r < NROWS) {
    const ushort4 m = *(const ushort4*)(U + (((size_t)(NROWS + (r >> 5))) << 10) + c);
    o.x = ((short)m.x > 0) ? u.x : 0;
    o.y = ((short)m.y > 0) ? u.y : 0;
    o.z = ((short)m.z > 0) ? u.z : 0;
    o.w = ((short)m.w > 0) ? u.w : 0;
  } else {
    o.x = ((short)u.x > 0) ? u.x : 0;
    o.y = ((short)u.y > 0) ? u.y : 0;
    o.z = ((short)u.z > 0) ? u.z : 0;
    o.w = ((short)u.w > 0) ? u.w : 0;
  }
  *(ushort4*)(outp + i4) = o;
}

// Fused prep: x fp32 -> bf16 A_enc; per-(b,n) weights from dist^2; zero out[0].
__global__ __launch_bounds__(256) void prep_kernel(
    const float* __restrict__ x_c, const float* __restrict__ x_nn,
    ushortT* __restrict__ A_enc, float* __restrict__ wbuf, float* __restrict__ out) {
  const int i = blockIdx.x;
  const int t = threadIdx.x;
  if (i < NROWS) {
    const float* src = x_nn + (size_t)i * D_DIM;
    const float* ctr = x_c + (size_t)(i >> 5) * D_DIM;
    ushortT* dst = A_enc + (size_t)i * D_DIM;
    float s = 0.f;
    for (int d = t * 4; d < D_DIM; d += 1024) {
      const float4 v = *(const float4*)(src + d);
      const float4 c = *(const float4*)(ctr + d);
      ushort4 o;
      o.x = f2bf(v.x); o.y = f2bf(v.y); o.z = f2bf(v.z); o.w = f2bf(v.w);
      *(ushort4*)(dst + d) = o;
      const float dx = v.x - c.x, dy = v.y - c.y, dz = v.z - c.z, dw = v.w - c.w;
      s += dx * dx + dy * dy + dz * dz + dw * dw;
    }
    __shared__ float red[256];
    red[t] = s;
    __syncthreads();
    for (int st = 128; st > 0; st >>= 1) {
      if (t < st) red[t] += red[t + st];
      __syncthreads();
    }
    if (t == 0) {
      wbuf[i] = (red[0] > 1e-24f) ? 1.0f : 0.5f;
      if (i == 0) out[0] = 0.f;
    }
  } else {
    const int r = i - NROWS;
    const float* src = x_c + (size_t)r * D_DIM;
    ushortT* dst = A_enc + (size_t)i * D_DIM;
    for (int d = t * 4; d < D_DIM; d += 1024) {
      const float4 v = *(const float4*)(src + d);
      ushort4 o;
      o.x = f2bf(v.x); o.y = f2bf(v.y); o.z = f2bf(v.z); o.w = f2bf(v.w);
      *(ushort4*)(dst + d) = o;
    }
  }
}

// Batched transpose+cast of all six weights: W (KxN f32) -> WT (NxK bf16).
__global__ __launch_bounds__(256) void trans_all(
    const float* __restrict__ We1, const float* __restrict__ We2,
    const float* __restrict__ We3, const float* __restrict__ Wd1,
    const float* __restrict__ Wd2, const float* __restrict__ Wd3,
    ushortT* __restrict__ We1T, ushortT* __restrict__ We2T,
    ushortT* __restrict__ We3T, ushortT* __restrict__ Wd1T,
    ushortT* __restrict__ Wd2T, ushortT* __restrict__ Wd3T) {
  const int b = blockIdx.x;
  const float* W; ushortT* WT; int K, N, loc;
  if (b < 3072)      { W = We1; WT = We1T; K = 3072; N = 1024; loc = b; }
  else if (b < 4096) { W = We2; WT = We2T; K = 1024; N = 1024; loc = b - 3072; }
  else if (b < 4128) { W = We3; WT = We3T; K = 1024; N = 32;   loc = b - 4096; }
  else if (b < 4160) { W = Wd1; WT = Wd1T; K = 32;   N = 1024; loc = b - 4128; }
  else if (b < 5184) { W = Wd2; WT = Wd2T; K = 1024; N = 1024; loc = b - 4160; }
  else               { W = Wd3; WT = Wd3T; K = 1024; N = 3072; loc = b - 5184; }
  const int ntiles = N >> 5;
  const int n0 = (loc % ntiles) * 32;
  const int k0 = (loc / ntiles) * 32;
  __shared__ float tile[32][33];
  const int tx = threadIdx.x & 31;
  const int ty = threadIdx.x >> 5;
  for (int i = ty; i < 32; i += 8)
    tile[i][tx] = W[(size_t)(k0 + i) * N + n0 + tx];
  __syncthreads();
  for (int i = ty; i < 32; i += 8)
    WT[(size_t)(n0 + i) * K + k0 + tx] = f2bf(tile[tx][i]);
}

extern "C" void kernel_launch(void* const* d_in, const int* in_sizes, int n_in,
                              void* d_out, int out_size, void* d_ws, size_t ws_size,
                              hipStream_t stream) {
  const float* x_c = (const float*)d_in[0];
  const float* x_nn = (const float*)d_in[1];
  const float* We1 = (const float*)d_in[2];
  const float* be1 = (const float*)d_in[3];
  const float* We2 = (const float*)d_in[4];
  const float* be2 = (const float*)d_in[5];
  const float* We3 = (const float*)d_in[6];
  const float* be3 = (const float*)d_in[7];
  const float* Wd1 = (const float*)d_in[8];
  const float* bd1 = (const float*)d_in[9];
  const float* Wd2 = (const float*)d_in[10];
  const float* bd2 = (const float*)d_in[11];
  const float* Wd3 = (const float*)d_in[12];
  const float* bd3 = (const float*)d_in[13];
  float* out = (float*)d_out;

  char* p = (char*)d_ws;
  auto alloc = [&](size_t bytes) {
    char* r = p;
    p += (bytes + 255) & ~(size_t)255;
    return r;
  };
  ushortT* We1T = (ushortT*)alloc((size_t)H_DIM * D_DIM * 2);
  ushortT* We2T = (ushortT*)alloc((size_t)H_DIM * H_DIM * 2);
  ushortT* We3T = (ushortT*)alloc((size_t)Z_DIM * H_DIM * 2);
  ushortT* Wd1T = (ushortT*)alloc((size_t)H_DIM * Z_DIM * 2);
  ushortT* Wd2T = (ushortT*)alloc((size_t)H_DIM * H_DIM * 2);
  ushortT* Wd3T = (ushortT*)alloc((size_t)D_DIM * H_DIM * 2);
  ushortT* A_enc = (ushortT*)alloc((size_t)MENC * D_DIM * 2);
  ushortT* bufX = (ushortT*)alloc((size_t)MENC * H_DIM * 2);  // h1 / U1 / U2
  ushortT* bufY = (ushortT*)alloc((size_t)MENC * H_DIM * 2);  // h2 / A2 / t2
  ushortT* z = (ushortT*)alloc((size_t)MENC * Z_DIM * 2);
  // shared split-K partial buffer: max(3 planes of MENCxH f32, 8 of MENCxZ)
  float* Pbig = (float*)alloc((size_t)3 * MENC * H_DIM * 4);
  float* wbuf = (float*)alloc((size_t)NROWS * 4);

  const dim3 blk(256);
  const float* nofp = nullptr;
  const ushortT* nobf = nullptr;

  // x -> bf16, per-neighbor weights, zero loss accumulator; weights -> bf16^T
  prep_kernel<<<dim3(MENC), blk, 0, stream>>>(x_c, x_nn, A_enc, wbuf, out);
  trans_all<<<dim3(8256), blk, 0, stream>>>(We1, We2, We3, Wd1, Wd2, Wd3,
                                            We1T, We2T, We3T, Wd1T, Wd2T, Wd3T);

  // enc1: h1 = relu(A_enc @ We1 + be1). Split-K S=3 -> 792 blocks (3/CU).
  gemm32<EP_PART, 128><<<dim3(8, 33, 3), blk, 0, stream>>>(
      A_enc, We1T, nofp, nullptr, Pbig, MENC, H_DIM, D_DIM, D_DIM / 3,
      nobf, nofp, nullptr);
  reduce_lin<3, 1><<<dim3((MENC * H_DIM) / 1024), blk, 0, stream>>>(
      Pbig, be1, bufX, MENC * H_DIM, H_DIM - 1);

  // enc2: h2 = relu(h1 @ We2 + be2). Split-K S=2 -> 528 blocks.
  gemm32<EP_PART, 128><<<dim3(8, 33, 2), blk, 0, stream>>>(
      bufX, We2T, nofp, nullptr, Pbig, MENC, H_DIM, H_DIM, H_DIM / 2,
      nobf, nofp, nullptr);
  reduce_lin<2, 1><<<dim3((MENC * H_DIM) / 1024), blk, 0, stream>>>(
      Pbig, be2, bufY, MENC * H_DIM, H_DIM - 1);

  // z = h2 @ We3 + be3 (N=32): split-K S=8 -> 264 blocks, 4 tiles each
  gemm32<EP_PART, 32><<<dim3(1, 33, 8), blk, 0, stream>>>(
      bufY, We3T, nofp, nullptr, Pbig, MENC, Z_DIM, H_DIM, H_DIM / 8,
      nobf, nofp, nullptr);
  reduce_lin<8, 0><<<dim3((MENC * Z_DIM) / 1024), blk, 0, stream>>>(
      Pbig, be3, z, MENC * Z_DIM, Z_DIM - 1);

  // linearized decoder with frozen center masks (exact for ReLU MLP):
  // U1 = [z_nn; z_c] @ Wd1 + bd1 (K=32, single tile)
  gemm_sb<EP_BIAS, 64><<<dim3(16, 33), blk, 0, stream>>>(
      z, Wd1T, bd1, bufX, MENC, H_DIM, Z_DIM, nobf, nofp, nullptr);
  // A2 = mask1 .* U1 (neighbors), relu(U1) (centers)
  mask_apply<<<dim3((MENC * H_DIM) / 1024), blk, 0, stream>>>(bufX, bufY);
  // U2 = A2 @ Wd2 + bd2 (raw, all rows). Split-K S=2.
  gemm32<EP_PART, 128><<<dim3(8, 33, 2), blk, 0, stream>>>(
      bufY, Wd2T, nofp, nullptr, Pbig, MENC, H_DIM, H_DIM, H_DIM / 2,
      nobf, nofp, nullptr);
  reduce_lin<2, 0><<<dim3((MENC * H_DIM) / 1024), blk, 0, stream>>>(
      Pbig, bd2, bufX, MENC * H_DIM, H_DIM - 1);
  // t2 = mask2 .* U2 (neighbor rows only)
  mask_apply<<<dim3((NROWS * H_DIM) / 1024), blk, 0, stream>>>(bufX, bufY);
  // loss GEMM: pred = t2 @ Wd3 + bd3, fused weighted-SSE vs bf16 x_nn
  // (768 blocks, 48KB LDS -> 3/CU)
  gemm32<EP_LOSS, 128><<<dim3(24, 32, 1), blk, 0, stream>>>(
      bufY, Wd3T, bd3, nullptr, nullptr, NROWS, D_DIM, H_DIM, H_DIM,
      A_enc, wbuf, out);
}